// Round 1
// baseline (66.150 us; speedup 1.0000x reference)
//
#include <hip/hip_runtime.h>

// OneHotEmbedding == row gather: out[i,:] = embeddings[inputs[i],:]
// N=16384, VOCAB=32000, EMB=128 (float32).
// One float4 (16 B) per thread: row = t>>5, col = t&31.
// 32 consecutive lanes share one index -> broadcast load; emb row read and
// out write are fully coalesced 16 B/lane.

#define N_ROWS 16384
#define EMB 128
#define EMB4 (EMB / 4)  // 32 float4 per row

__global__ __launch_bounds__(256) void OneHotEmbedding_87522843561070_kernel(
    const int* __restrict__ idx,
    const float4* __restrict__ emb,
    float4* __restrict__ out) {
    int t = blockIdx.x * blockDim.x + threadIdx.x;  // 0 .. N_ROWS*EMB4-1
    int row = t >> 5;
    int col = t & 31;
    int e = idx[row];
    out[t] = emb[(long)e * EMB4 + col];
}

extern "C" void kernel_launch(void* const* d_in, const int* in_sizes, int n_in,
                              void* d_out, int out_size, void* d_ws, size_t ws_size,
                              hipStream_t stream) {
    const int* idx = (const int*)d_in[0];
    const float4* emb = (const float4*)d_in[1];
    float4* out = (float4*)d_out;

    const int total = N_ROWS * EMB4;       // 524288 float4 elements
    const int block = 256;
    const int grid = total / block;        // 2048 blocks

    OneHotEmbedding_87522843561070_kernel<<<grid, block, 0, stream>>>(idx, emb, out);
}